// Round 6
// baseline (956.601 us; speedup 1.0000x reference)
//
#include <hip/hip_runtime.h>

#pragma clang fp contract(off)

#define HQ 384
#define WQ 384
#define NC 64
#define HFD 48
#define HID 256
#define NPIX (4 * HQ * WQ)
#define PPB 64   // pixels per block

typedef _Float16 half8 __attribute__((ext_vector_type(8)));
typedef float f32x4 __attribute__((ext_vector_type(4)));
typedef unsigned int u32;
typedef unsigned short u16;

// ws layout in u32 units: per layer, A=W^T fragments, hi then lo(residual).
// entry index = ((t*NS + s)*64 + lane)*4 + i ; L0: NT=16,NS=3 ; L1-3: NT=16,NS=8
#define O0H 0
#define O0L 12288
#define O1H 24576
#define O1L 57344
#define O2H 90112
#define O2L 122880
#define O3H 155648
#define O3L 188416
// total 221184 u32 = 884736 bytes of d_ws used

__device__ __forceinline__ u16 h16(float x) {
    return __builtin_bit_cast(u16, (_Float16)x);     // RNE
}
__device__ __forceinline__ u32 pk(u16 a, u16 b) { return (u32)a | ((u32)b << 16); }
__device__ __forceinline__ float f16lo(u32 v) {
    return (float)__builtin_bit_cast(_Float16, (u16)(v & 0xffffu));
}
__device__ __forceinline__ float f16hi(u32 v) {
    return (float)__builtin_bit_cast(_Float16, (u16)(v >> 16));
}

// ---------------------------------------------------------------------------
// Nearest-sample index per grid_sample(nearest, align_corners=False).
// Exact f32 op sequence (contraction off file-wide). Validated on HW (r3/r5).
// ---------------------------------------------------------------------------
__device__ __forceinline__ int nearest_idx(float g, bool& valid) {
    float t  = (g + 1.0f) * 48.0f;
    float ix = (t - 1.0f) * 0.5f;
    float r  = rintf(ix);          // round half to even
    int   i  = (int)r;
    if (i < 0 || i > 47) valid = false;
    return i < 0 ? 0 : (i > 47 ? 47 : i);
}

// ---------------------------------------------------------------------------
// Weight pre-pack: A = W^T as MFMA A-fragments. hi = f16 RNE(w),
// lo = f16(w - (f32)hi) UNSCALED (may be subnormal) -> accumulates directly.
// lane: row j' = 16t + (lane&15), k = 32s + 8*(lane>>4) + 2i (+1)
// ---------------------------------------------------------------------------
extern "C" __global__ void __launch_bounds__(256)
pack_w(const float* __restrict__ W0, const float* __restrict__ W1,
       const float* __restrict__ W2, const float* __restrict__ W3,
       u32* __restrict__ ws) {
    int gid = blockIdx.x * 256 + threadIdx.x;   // 0..110591
    const float* W; int NS, K, oh, ol, rem;
    if (gid < 12288)      { W = W0; NS = 3; K = 71;  oh = O0H; ol = O0L; rem = gid; }
    else if (gid < 45056) { W = W1; NS = 8; K = 256; oh = O1H; ol = O1L; rem = gid - 12288; }
    else if (gid < 77824) { W = W2; NS = 8; K = 256; oh = O2H; ol = O2L; rem = gid - 45056; }
    else                  { W = W3; NS = 8; K = 256; oh = O3H; ol = O3L; rem = gid - 77824; }
    int i = rem & 3, lane = (rem >> 2) & 63, ts = rem >> 8;
    int s = ts % NS, t = ts / NS;
    int jp = t * 16 + (lane & 15);
    int k0 = s * 32 + (lane >> 4) * 8 + 2 * i;
    float w0 = (k0 < K)     ? W[(size_t)k0 * HID + jp]       : 0.0f;
    float w1 = (k0 + 1 < K) ? W[(size_t)(k0 + 1) * HID + jp] : 0.0f;
    _Float16 h0 = (_Float16)w0, h1 = (_Float16)w1;
    _Float16 l0 = (_Float16)(w0 - (float)h0);
    _Float16 l1 = (_Float16)(w1 - (float)h1);
    ws[oh + rem] = pk(__builtin_bit_cast(u16, h0), __builtin_bit_cast(u16, h1));
    ws[ol + rem] = pk(__builtin_bit_cast(u16, l0), __builtin_bit_cast(u16, l1));
}

// ---------------------------------------------------------------------------
// One MFMA MLP layer: act' = relu(W^T · act + b), act in LDS as f16 (hi only).
// LDS: [64 rows(px)][32 units(16B = 8 f16)], swizzle unit' = u ^ (px & 31).
// Wave owns 4 j'-tiles (T = wave*4+tt) x all 4 px-tiles.
// Per k-step: acc = mfma(wlo,b,acc); acc = mfma(whi,b,acc)  -- no VALU fixup.
// ---------------------------------------------------------------------------
template <int NS>
__device__ __forceinline__ void mfma_layer(
    const u32* __restrict__ whi, const u32* __restrict__ wlo,
    const float* __restrict__ bias,
    u32* __restrict__ sAct, int wave, int lane) {
    const int r = lane & 15, g = lane >> 4;
    f32x4 acc[4][4];
#pragma unroll
    for (int a = 0; a < 4; ++a)
#pragma unroll
        for (int b = 0; b < 4; ++b) acc[a][b] = f32x4{0.0f, 0.0f, 0.0f, 0.0f};

    for (int s = 0; s < NS; ++s) {
        half8 ah[4], al[4];
#pragma unroll
        for (int tt = 0; tt < 4; ++tt) {
            int idx = (((wave * 4 + tt) * NS + s) * 64 + lane) * 4;
            ah[tt] = __builtin_bit_cast(half8, *(const uint4*)(whi + idx));
            al[tt] = __builtin_bit_cast(half8, *(const uint4*)(wlo + idx));
        }
#pragma unroll
        for (int p = 0; p < 4; ++p) {
            int rr = p * 16 + r;
            int u = (s * 4 + g) ^ (rr & 31);
            half8 bh = __builtin_bit_cast(half8, *(const uint4*)(sAct + rr * 128 + u * 4));
#pragma unroll
            for (int tt = 0; tt < 4; ++tt) {
                acc[tt][p] = __builtin_amdgcn_mfma_f32_16x16x32_f16(al[tt], bh, acc[tt][p], 0, 0, 0);
                acc[tt][p] = __builtin_amdgcn_mfma_f32_16x16x32_f16(ah[tt], bh, acc[tt][p], 0, 0, 0);
            }
        }
    }
    __syncthreads();   // all reads of sAct done before overwrite

    // epilogue: bias + relu + f16 RNE + LDS write
    // D mapping: col px = 16p + (lane&15), row j' = 16T + 4g + e
#pragma unroll
    for (int tt = 0; tt < 4; ++tt) {
        int T = wave * 4 + tt;
        int jb = T * 16 + g * 4;
        float bv0 = bias[jb + 0], bv1 = bias[jb + 1];
        float bv2 = bias[jb + 2], bv3 = bias[jb + 3];
#pragma unroll
        for (int p = 0; p < 4; ++p) {
            float v0 = fmaxf(acc[tt][p][0] + bv0, 0.0f);
            float v1 = fmaxf(acc[tt][p][1] + bv1, 0.0f);
            float v2 = fmaxf(acc[tt][p][2] + bv2, 0.0f);
            float v3 = fmaxf(acc[tt][p][3] + bv3, 0.0f);
            int rr = p * 16 + r;
            int u = (2 * T + (g >> 1)) ^ (rr & 31);
            int a = rr * 128 + u * 4 + (g & 1) * 2;
            sAct[a]     = pk(h16(v0), h16(v1));
            sAct[a + 1] = pk(h16(v2), h16(v3));
        }
    }
    __syncthreads();
}

// ---------------------------------------------------------------------------
// Fused LIIF kernel: feature build -> 4 MFMA layers -> small final layer.
// ---------------------------------------------------------------------------
extern "C" __global__ void __launch_bounds__(256, 4)
liif_mfma(const float* __restrict__ x, const float* __restrict__ coord,
          const float* __restrict__ cell, const float* __restrict__ lr,
          const float* __restrict__ b0, const float* __restrict__ b1,
          const float* __restrict__ b2, const float* __restrict__ b3,
          const float* __restrict__ W4, const float* __restrict__ b4,
          const u32* __restrict__ ws, float* __restrict__ out) {
    __shared__ u32 sAct[PPB * 128];   // 32 KB -> 4 blocks/CU possible
    const int tid = threadIdx.x;
    const int wave = tid >> 6, lane = tid & 63;

    // ---------------- stage 1: 71-dim feature -> LDS f16 --------------------
    {
        const int px = tid >> 2, sub = tid & 3;
        const int gg = blockIdx.x * PPB + px;
        const int b = gg / (HQ * WQ);
        const float gy = coord[(size_t)gg * 2 + 0];
        const float gx = coord[(size_t)gg * 2 + 1];
        bool vmain = true;
        const int ixn = nearest_idx(gx, vmain);
        const int iyn = nearest_idx(gy, vmain);

        // 16 q_feat channels per thread -> logical units 2*sub, 2*sub+1
        const float* xb = x + (((size_t)b * NC) * HFD + iyn) * HFD + ixn;
        u32 hbuf[8];
#pragma unroll
        for (int e = 0; e < 8; ++e) {
            int c = sub * 16 + e * 2;
            float v0 = vmain ? xb[(size_t)c * (HFD * HFD)] : 0.0f;
            float v1 = vmain ? xb[(size_t)(c + 1) * (HFD * HFD)] : 0.0f;
            hbuf[e] = pk(h16(v0), h16(v1));
        }
        {
            int u = (2 * sub) ^ (px & 31);
            *(uint4*)(sAct + px * 128 + u * 4) = make_uint4(hbuf[0], hbuf[1], hbuf[2], hbuf[3]);
            u = (2 * sub + 1) ^ (px & 31);
            *(uint4*)(sAct + px * 128 + u * 4) = make_uint4(hbuf[4], hbuf[5], hbuf[6], hbuf[7]);
        }
        if (sub == 0) {
            // extras: j = 64..71 -> logical unit 8
            float qyc = vmain ? ((2.0f * (float)iyn + 1.0f) / 48.0f - 1.0f) : 0.0f;
            float qxc = vmain ? ((2.0f * (float)ixn + 1.0f) / 48.0f - 1.0f) : 0.0f;
            float f64v = (gy - qyc) * 48.0f;
            float f65v = (gx - qxc) * 48.0f;
            float f66v = cell[b * 2 + 0] * 48.0f;
            float f67v = cell[b * 2 + 1] * 48.0f;

            // rgb_std over 4 diagonally shifted nearest LR samples (ddof=1)
            const float c148 = (float)(1.0 / 48.0);
            const float LO = (float)(-1.0 + 1e-6);
            const float HI = (float)(1.0 - 1e-6);
            float v[4][3];
#pragma unroll
            for (int a = 0; a < 2; ++a) {
                const float vx = (a == 0) ? -c148 : c148;
#pragma unroll
                for (int qq = 0; qq < 2; ++qq) {
                    const float vy = (qq == 0) ? -c148 : c148;
                    float cy = (gy + vx) + 1e-6f;
                    cy = fminf(fmaxf(cy, LO), HI);
                    float cx = (gx + vy) + 1e-6f;
                    cx = fminf(fmaxf(cx, LO), HI);
                    bool vv = true;
                    int jx = nearest_idx(cx, vv);
                    int jy = nearest_idx(cy, vv);
                    int si = a * 2 + qq;
#pragma unroll
                    for (int ch = 0; ch < 3; ++ch)
                        v[si][ch] = vv ? lr[(((size_t)b * 3 + ch) * HFD + jy) * HFD + jx] : 0.0f;
                }
            }
            float sd[3];
#pragma unroll
            for (int ch = 0; ch < 3; ++ch) {
                float mean = (((v[0][ch] + v[1][ch]) + v[2][ch]) + v[3][ch]) / 4.0f;
                float d0 = v[0][ch] - mean, d1 = v[1][ch] - mean;
                float d2 = v[2][ch] - mean, d3 = v[3][ch] - mean;
                float var = (((d0 * d0 + d1 * d1) + d2 * d2) + d3 * d3) / 3.0f;
                sd[ch] = sqrtf(var);
            }
            int u = 8 ^ (px & 31);
            *(uint4*)(sAct + px * 128 + u * 4) =
                make_uint4(pk(h16(f64v), h16(f65v)), pk(h16(f66v), h16(f67v)),
                           pk(h16(sd[0]), h16(sd[1])), pk(h16(sd[2]), 0));
        } else {
            // zero-pad logical units 9..11 (k = 72..95)
            int u = (8 + sub) ^ (px & 31);
            *(uint4*)(sAct + px * 128 + u * 4) = make_uint4(0, 0, 0, 0);
        }
    }
    __syncthreads();

    // ---------------- 4 hidden layers on the matrix pipe --------------------
    mfma_layer<3>(ws + O0H, ws + O0L, b0, sAct, wave, lane);
    mfma_layer<8>(ws + O1H, ws + O1L, b1, sAct, wave, lane);
    mfma_layer<8>(ws + O2H, ws + O2L, b2, sAct, wave, lane);
    mfma_layer<8>(ws + O3H, ws + O3L, b3, sAct, wave, lane);

    // ---------------- final 256 -> 3 (VALU, tiny) ---------------------------
    if (tid < PPB * 3) {
        int px = tid / 3, o = tid - px * 3;
        float acc = 0.0f;
        for (int u = 0; u < 32; ++u) {
            int up = u ^ (px & 31);
            const u32* ph = sAct + px * 128 + up * 4;
#pragma unroll
            for (int uu = 0; uu < 4; ++uu) {
                u32 hv = ph[uu];
                int j = u * 8 + uu * 2;
                acc = __builtin_fmaf(f16lo(hv), W4[j * 3 + o], acc);
                acc = __builtin_fmaf(f16hi(hv), W4[(j + 1) * 3 + o], acc);
            }
        }
        acc += b4[o];
        int gg = blockIdx.x * PPB + px;
        int b = gg / (HQ * WQ);
        int rem = gg - b * (HQ * WQ);
        out[((size_t)(b * 3 + o)) * (HQ * WQ) + rem] = acc;
    }
}

extern "C" void kernel_launch(void* const* d_in, const int* in_sizes, int n_in,
                              void* d_out, int out_size, void* d_ws, size_t ws_size,
                              hipStream_t stream) {
    const float* x     = (const float*)d_in[0];
    const float* coord = (const float*)d_in[1];
    const float* cell  = (const float*)d_in[2];
    const float* lr    = (const float*)d_in[3];
    const float* W0    = (const float*)d_in[4];
    const float* b0    = (const float*)d_in[5];
    const float* W1    = (const float*)d_in[6];
    const float* b1    = (const float*)d_in[7];
    const float* W2    = (const float*)d_in[8];
    const float* b2    = (const float*)d_in[9];
    const float* W3    = (const float*)d_in[10];
    const float* b3    = (const float*)d_in[11];
    const float* W4    = (const float*)d_in[12];
    const float* b4    = (const float*)d_in[13];
    u32* ws = (u32*)d_ws;

    pack_w<<<dim3(432), dim3(256), 0, stream>>>(W0, W1, W2, W3, ws);
    liif_mfma<<<dim3(NPIX / PPB), dim3(256), 0, stream>>>(
        x, coord, cell, lr, b0, b1, b2, b3, W4, b4, ws, (float*)d_out);
}

// Round 7
// 739.075 us; speedup vs baseline: 1.2943x; 1.2943x over previous
//
#include <hip/hip_runtime.h>

#pragma clang fp contract(off)

#define HQ 384
#define WQ 384
#define NC 64
#define HFD 48
#define HID 256
#define NPIX (4 * HQ * WQ)
#define PPB 64   // pixels per block

typedef _Float16 half8 __attribute__((ext_vector_type(8)));
typedef float f32x4 __attribute__((ext_vector_type(4)));
typedef unsigned int u32;
typedef unsigned short u16;

// ws layout in u32 units: per layer, A=W^T fragments, hi then lo(residual).
// entry index = ((t*NS + s)*64 + lane)*4 + i ; L0: NT=16,NS=3 ; L1-3: NT=16,NS=8
#define O0H 0
#define O0L 12288
#define O1H 24576
#define O1L 57344
#define O2H 90112
#define O2L 122880
#define O3H 155648
#define O3L 188416
// total 221184 u32 = 884736 bytes of d_ws used

__device__ __forceinline__ u16 h16(float x) {
    return __builtin_bit_cast(u16, (_Float16)x);     // RNE
}
__device__ __forceinline__ u32 pk(u16 a, u16 b) { return (u32)a | ((u32)b << 16); }
__device__ __forceinline__ float f16lo(u32 v) {
    return (float)__builtin_bit_cast(_Float16, (u16)(v & 0xffffu));
}
__device__ __forceinline__ float f16hi(u32 v) {
    return (float)__builtin_bit_cast(_Float16, (u16)(v >> 16));
}

// ---------------------------------------------------------------------------
// Nearest-sample index per grid_sample(nearest, align_corners=False).
// Exact f32 op sequence (contraction off file-wide). Validated on HW (r3/r5).
// ---------------------------------------------------------------------------
__device__ __forceinline__ int nearest_idx(float g, bool& valid) {
    float t  = (g + 1.0f) * 48.0f;
    float ix = (t - 1.0f) * 0.5f;
    float r  = rintf(ix);          // round half to even
    int   i  = (int)r;
    if (i < 0 || i > 47) valid = false;
    return i < 0 ? 0 : (i > 47 ? 47 : i);
}

// ---------------------------------------------------------------------------
// Weight pre-pack: A = W^T as MFMA A-fragments. hi = f16 RNE(w),
// lo = f16(w - (f32)hi) UNSCALED (may be subnormal) -> accumulates directly.
// lane: row j' = 16t + (lane&15), k = 32s + 8*(lane>>4) + 2i (+1)
// ---------------------------------------------------------------------------
extern "C" __global__ void __launch_bounds__(256)
pack_w(const float* __restrict__ W0, const float* __restrict__ W1,
       const float* __restrict__ W2, const float* __restrict__ W3,
       u32* __restrict__ ws) {
    int gid = blockIdx.x * 256 + threadIdx.x;   // 0..110591
    const float* W; int NS, K, oh, ol, rem;
    if (gid < 12288)      { W = W0; NS = 3; K = 71;  oh = O0H; ol = O0L; rem = gid; }
    else if (gid < 45056) { W = W1; NS = 8; K = 256; oh = O1H; ol = O1L; rem = gid - 12288; }
    else if (gid < 77824) { W = W2; NS = 8; K = 256; oh = O2H; ol = O2L; rem = gid - 45056; }
    else                  { W = W3; NS = 8; K = 256; oh = O3H; ol = O3L; rem = gid - 77824; }
    int i = rem & 3, lane = (rem >> 2) & 63, ts = rem >> 8;
    int s = ts % NS, t = ts / NS;
    int jp = t * 16 + (lane & 15);
    int k0 = s * 32 + (lane >> 4) * 8 + 2 * i;
    float w0 = (k0 < K)     ? W[(size_t)k0 * HID + jp]       : 0.0f;
    float w1 = (k0 + 1 < K) ? W[(size_t)(k0 + 1) * HID + jp] : 0.0f;
    _Float16 h0 = (_Float16)w0, h1 = (_Float16)w1;
    _Float16 l0 = (_Float16)(w0 - (float)h0);
    _Float16 l1 = (_Float16)(w1 - (float)h1);
    ws[oh + rem] = pk(__builtin_bit_cast(u16, h0), __builtin_bit_cast(u16, h1));
    ws[ol + rem] = pk(__builtin_bit_cast(u16, l0), __builtin_bit_cast(u16, l1));
}

// ---------------------------------------------------------------------------
// One MFMA MLP layer: act' = relu(W^T · act + b), act in LDS as f16 (hi only).
// LDS: [64 rows(px)][32 units(16B = 8 f16)], swizzle unit' = u ^ (px & 31).
// Wave owns 4 j'-tiles (T = wave*4+tt) x all 4 px-tiles.
// Per k-step: acc = mfma(wlo,b,acc); acc = mfma(whi,b,acc)  -- no VALU fixup.
// ---------------------------------------------------------------------------
template <int NS>
__device__ __forceinline__ void mfma_layer(
    const u32* __restrict__ whi, const u32* __restrict__ wlo,
    const float* __restrict__ bias,
    u32* __restrict__ sAct, int wave, int lane) {
    const int r = lane & 15, g = lane >> 4;
    f32x4 acc[4][4];
#pragma unroll
    for (int a = 0; a < 4; ++a)
#pragma unroll
        for (int b = 0; b < 4; ++b) acc[a][b] = f32x4{0.0f, 0.0f, 0.0f, 0.0f};

    for (int s = 0; s < NS; ++s) {
        half8 ah[4], al[4];
#pragma unroll
        for (int tt = 0; tt < 4; ++tt) {
            int idx = (((wave * 4 + tt) * NS + s) * 64 + lane) * 4;
            ah[tt] = __builtin_bit_cast(half8, *(const uint4*)(whi + idx));
            al[tt] = __builtin_bit_cast(half8, *(const uint4*)(wlo + idx));
        }
#pragma unroll
        for (int p = 0; p < 4; ++p) {
            int rr = p * 16 + r;
            int u = (s * 4 + g) ^ (rr & 31);
            half8 bh = __builtin_bit_cast(half8, *(const uint4*)(sAct + rr * 128 + u * 4));
#pragma unroll
            for (int tt = 0; tt < 4; ++tt) {
                acc[tt][p] = __builtin_amdgcn_mfma_f32_16x16x32_f16(al[tt], bh, acc[tt][p], 0, 0, 0);
                acc[tt][p] = __builtin_amdgcn_mfma_f32_16x16x32_f16(ah[tt], bh, acc[tt][p], 0, 0, 0);
            }
        }
    }
    __syncthreads();   // all reads of sAct done before overwrite

    // epilogue: bias + relu + f16 RNE + LDS write
    // D mapping: col px = 16p + (lane&15), row j' = 16T + 4g + e
#pragma unroll
    for (int tt = 0; tt < 4; ++tt) {
        int T = wave * 4 + tt;
        int jb = T * 16 + g * 4;
        float bv0 = bias[jb + 0], bv1 = bias[jb + 1];
        float bv2 = bias[jb + 2], bv3 = bias[jb + 3];
#pragma unroll
        for (int p = 0; p < 4; ++p) {
            float v0 = fmaxf(acc[tt][p][0] + bv0, 0.0f);
            float v1 = fmaxf(acc[tt][p][1] + bv1, 0.0f);
            float v2 = fmaxf(acc[tt][p][2] + bv2, 0.0f);
            float v3 = fmaxf(acc[tt][p][3] + bv3, 0.0f);
            int rr = p * 16 + r;
            int u = (2 * T + (g >> 1)) ^ (rr & 31);
            int a = rr * 128 + u * 4 + (g & 1) * 2;
            sAct[a]     = pk(h16(v0), h16(v1));
            sAct[a + 1] = pk(h16(v2), h16(v3));
        }
    }
    __syncthreads();
}

// ---------------------------------------------------------------------------
// Fused LIIF kernel: feature build -> 4 MFMA layers -> small final layer.
// launch_bounds(256,3): cap 512/3=170 regs >= ~145 demand -> NO SPILL.
// (256,4) spilled: 1.25 GB scratch writes = the whole r6 runtime. [r6 PMC]
// ---------------------------------------------------------------------------
extern "C" __global__ void __launch_bounds__(256, 3)
liif_mfma(const float* __restrict__ x, const float* __restrict__ coord,
          const float* __restrict__ cell, const float* __restrict__ lr,
          const float* __restrict__ b0, const float* __restrict__ b1,
          const float* __restrict__ b2, const float* __restrict__ b3,
          const float* __restrict__ W4, const float* __restrict__ b4,
          const u32* __restrict__ ws, float* __restrict__ out) {
    __shared__ u32 sAct[PPB * 128];   // 32 KB
    const int tid = threadIdx.x;
    const int wave = tid >> 6, lane = tid & 63;

    // ---------------- stage 1: 71-dim feature -> LDS f16 --------------------
    {
        const int px = tid >> 2, sub = tid & 3;
        const int gg = blockIdx.x * PPB + px;
        const int b = gg / (HQ * WQ);
        const float gy = coord[(size_t)gg * 2 + 0];
        const float gx = coord[(size_t)gg * 2 + 1];
        bool vmain = true;
        const int ixn = nearest_idx(gx, vmain);
        const int iyn = nearest_idx(gy, vmain);

        // 16 q_feat channels per thread -> logical units 2*sub, 2*sub+1
        const float* xb = x + (((size_t)b * NC) * HFD + iyn) * HFD + ixn;
        u32 hbuf[8];
#pragma unroll
        for (int e = 0; e < 8; ++e) {
            int c = sub * 16 + e * 2;
            float v0 = vmain ? xb[(size_t)c * (HFD * HFD)] : 0.0f;
            float v1 = vmain ? xb[(size_t)(c + 1) * (HFD * HFD)] : 0.0f;
            hbuf[e] = pk(h16(v0), h16(v1));
        }
        {
            int u = (2 * sub) ^ (px & 31);
            *(uint4*)(sAct + px * 128 + u * 4) = make_uint4(hbuf[0], hbuf[1], hbuf[2], hbuf[3]);
            u = (2 * sub + 1) ^ (px & 31);
            *(uint4*)(sAct + px * 128 + u * 4) = make_uint4(hbuf[4], hbuf[5], hbuf[6], hbuf[7]);
        }
        if (sub == 0) {
            // extras: j = 64..71 -> logical unit 8
            float qyc = vmain ? ((2.0f * (float)iyn + 1.0f) / 48.0f - 1.0f) : 0.0f;
            float qxc = vmain ? ((2.0f * (float)ixn + 1.0f) / 48.0f - 1.0f) : 0.0f;
            float f64v = (gy - qyc) * 48.0f;
            float f65v = (gx - qxc) * 48.0f;
            float f66v = cell[b * 2 + 0] * 48.0f;
            float f67v = cell[b * 2 + 1] * 48.0f;

            // rgb_std over 4 diagonally shifted nearest LR samples (ddof=1)
            const float c148 = (float)(1.0 / 48.0);
            const float LO = (float)(-1.0 + 1e-6);
            const float HI = (float)(1.0 - 1e-6);
            float v[4][3];
#pragma unroll
            for (int a = 0; a < 2; ++a) {
                const float vx = (a == 0) ? -c148 : c148;
#pragma unroll
                for (int qq = 0; qq < 2; ++qq) {
                    const float vy = (qq == 0) ? -c148 : c148;
                    float cy = (gy + vx) + 1e-6f;
                    cy = fminf(fmaxf(cy, LO), HI);
                    float cx = (gx + vy) + 1e-6f;
                    cx = fminf(fmaxf(cx, LO), HI);
                    bool vv = true;
                    int jx = nearest_idx(cx, vv);
                    int jy = nearest_idx(cy, vv);
                    int si = a * 2 + qq;
#pragma unroll
                    for (int ch = 0; ch < 3; ++ch)
                        v[si][ch] = vv ? lr[(((size_t)b * 3 + ch) * HFD + jy) * HFD + jx] : 0.0f;
                }
            }
            float sd[3];
#pragma unroll
            for (int ch = 0; ch < 3; ++ch) {
                float mean = (((v[0][ch] + v[1][ch]) + v[2][ch]) + v[3][ch]) / 4.0f;
                float d0 = v[0][ch] - mean, d1 = v[1][ch] - mean;
                float d2 = v[2][ch] - mean, d3 = v[3][ch] - mean;
                float var = (((d0 * d0 + d1 * d1) + d2 * d2) + d3 * d3) / 3.0f;
                sd[ch] = sqrtf(var);
            }
            int u = 8 ^ (px & 31);
            *(uint4*)(sAct + px * 128 + u * 4) =
                make_uint4(pk(h16(f64v), h16(f65v)), pk(h16(f66v), h16(f67v)),
                           pk(h16(sd[0]), h16(sd[1])), pk(h16(sd[2]), 0));
        } else {
            // zero-pad logical units 9..11 (k = 72..95)
            int u = (8 + sub) ^ (px & 31);
            *(uint4*)(sAct + px * 128 + u * 4) = make_uint4(0, 0, 0, 0);
        }
    }
    __syncthreads();

    // ---------------- 4 hidden layers on the matrix pipe --------------------
    mfma_layer<3>(ws + O0H, ws + O0L, b0, sAct, wave, lane);
    mfma_layer<8>(ws + O1H, ws + O1L, b1, sAct, wave, lane);
    mfma_layer<8>(ws + O2H, ws + O2L, b2, sAct, wave, lane);
    mfma_layer<8>(ws + O3H, ws + O3L, b3, sAct, wave, lane);

    // ---------------- final 256 -> 3 (VALU, tiny) ---------------------------
    if (tid < PPB * 3) {
        int px = tid / 3, o = tid - px * 3;
        float acc = 0.0f;
        for (int u = 0; u < 32; ++u) {
            int up = u ^ (px & 31);
            const u32* ph = sAct + px * 128 + up * 4;
#pragma unroll
            for (int uu = 0; uu < 4; ++uu) {
                u32 hv = ph[uu];
                int j = u * 8 + uu * 2;
                acc = __builtin_fmaf(f16lo(hv), W4[j * 3 + o], acc);
                acc = __builtin_fmaf(f16hi(hv), W4[(j + 1) * 3 + o], acc);
            }
        }
        acc += b4[o];
        int gg = blockIdx.x * PPB + px;
        int b = gg / (HQ * WQ);
        int rem = gg - b * (HQ * WQ);
        out[((size_t)(b * 3 + o)) * (HQ * WQ) + rem] = acc;
    }
}

extern "C" void kernel_launch(void* const* d_in, const int* in_sizes, int n_in,
                              void* d_out, int out_size, void* d_ws, size_t ws_size,
                              hipStream_t stream) {
    const float* x     = (const float*)d_in[0];
    const float* coord = (const float*)d_in[1];
    const float* cell  = (const float*)d_in[2];
    const float* lr    = (const float*)d_in[3];
    const float* W0    = (const float*)d_in[4];
    const float* b0    = (const float*)d_in[5];
    const float* W1    = (const float*)d_in[6];
    const float* b1    = (const float*)d_in[7];
    const float* W2    = (const float*)d_in[8];
    const float* b2    = (const float*)d_in[9];
    const float* W3    = (const float*)d_in[10];
    const float* b3    = (const float*)d_in[11];
    const float* W4    = (const float*)d_in[12];
    const float* b4    = (const float*)d_in[13];
    u32* ws = (u32*)d_ws;

    pack_w<<<dim3(432), dim3(256), 0, stream>>>(W0, W1, W2, W3, ws);
    liif_mfma<<<dim3(NPIX / PPB), dim3(256), 0, stream>>>(
        x, coord, cell, lr, b0, b1, b2, b3, W4, b4, ws, (float*)d_out);
}

// Round 8
// 630.647 us; speedup vs baseline: 1.5169x; 1.1719x over previous
//
#include <hip/hip_runtime.h>

#pragma clang fp contract(off)

#define HQ 384
#define WQ 384
#define NC 64
#define HFD 48
#define HID 256
#define NPIX (4 * HQ * WQ)
#define PPB 64   // pixels per block
#define NTHR 512 // 8 waves; each wave owns 2 j'-tiles x 4 px-tiles

typedef _Float16 half8 __attribute__((ext_vector_type(8)));
typedef float f32x4 __attribute__((ext_vector_type(4)));
typedef unsigned int u32;
typedef unsigned short u16;

// ws layout in u32 units: per layer, A=W^T fragments, hi then lo(residual).
// entry index = ((T*NS + s)*64 + lane)*4 + i ; L0: NT=16,NS=3 ; L1-3: NT=16,NS=8
#define O0H 0
#define O0L 12288
#define O1H 24576
#define O1L 57344
#define O2H 90112
#define O2L 122880
#define O3H 155648
#define O3L 188416
// total 221184 u32 = 884736 bytes of d_ws used

__device__ __forceinline__ u16 h16(float x) {
    return __builtin_bit_cast(u16, (_Float16)x);     // RNE
}
__device__ __forceinline__ u32 pk(u16 a, u16 b) { return (u32)a | ((u32)b << 16); }
__device__ __forceinline__ float f16lo(u32 v) {
    return (float)__builtin_bit_cast(_Float16, (u16)(v & 0xffffu));
}
__device__ __forceinline__ float f16hi(u32 v) {
    return (float)__builtin_bit_cast(_Float16, (u16)(v >> 16));
}

// ---------------------------------------------------------------------------
// Nearest-sample index per grid_sample(nearest, align_corners=False).
// Exact f32 op sequence (contraction off file-wide). Validated on HW (r3/r5).
// ---------------------------------------------------------------------------
__device__ __forceinline__ int nearest_idx(float g, bool& valid) {
    float t  = (g + 1.0f) * 48.0f;
    float ix = (t - 1.0f) * 0.5f;
    float r  = rintf(ix);          // round half to even
    int   i  = (int)r;
    if (i < 0 || i > 47) valid = false;
    return i < 0 ? 0 : (i > 47 ? 47 : i);
}

// ---------------------------------------------------------------------------
// Weight pre-pack: A = W^T as MFMA A-fragments. hi = f16 RNE(w),
// lo = f16(w - (f32)hi) UNSCALED (subnormal-capable) -> accumulates directly.
// lane: row j' = 16T + (lane&15), k = 32s + 8*(lane>>4) + 2i (+1)
// ---------------------------------------------------------------------------
extern "C" __global__ void __launch_bounds__(256)
pack_w(const float* __restrict__ W0, const float* __restrict__ W1,
       const float* __restrict__ W2, const float* __restrict__ W3,
       u32* __restrict__ ws) {
    int gid = blockIdx.x * 256 + threadIdx.x;   // 0..110591
    const float* W; int NS, K, oh, ol, rem;
    if (gid < 12288)      { W = W0; NS = 3; K = 71;  oh = O0H; ol = O0L; rem = gid; }
    else if (gid < 45056) { W = W1; NS = 8; K = 256; oh = O1H; ol = O1L; rem = gid - 12288; }
    else if (gid < 77824) { W = W2; NS = 8; K = 256; oh = O2H; ol = O2L; rem = gid - 45056; }
    else                  { W = W3; NS = 8; K = 256; oh = O3H; ol = O3L; rem = gid - 77824; }
    int i = rem & 3, lane = (rem >> 2) & 63, ts = rem >> 8;
    int s = ts % NS, t = ts / NS;
    int jp = t * 16 + (lane & 15);
    int k0 = s * 32 + (lane >> 4) * 8 + 2 * i;
    float w0 = (k0 < K)     ? W[(size_t)k0 * HID + jp]       : 0.0f;
    float w1 = (k0 + 1 < K) ? W[(size_t)(k0 + 1) * HID + jp] : 0.0f;
    _Float16 h0 = (_Float16)w0, h1 = (_Float16)w1;
    _Float16 l0 = (_Float16)(w0 - (float)h0);
    _Float16 l1 = (_Float16)(w1 - (float)h1);
    ws[oh + rem] = pk(__builtin_bit_cast(u16, h0), __builtin_bit_cast(u16, h1));
    ws[ol + rem] = pk(__builtin_bit_cast(u16, l0), __builtin_bit_cast(u16, l1));
}

// ---------------------------------------------------------------------------
// One MFMA MLP layer: act' = relu(W^T · act + b), act in LDS as f16 (hi only).
// LDS: [64 rows(px)][32 units(16B = 8 f16)], swizzle unit' = u ^ (px & 31).
// 8 waves; wave owns 2 j'-tiles (T = wave*2+tt) x all 4 px-tiles.
// acc[2][4] = 32 AGPR; live weights 2tt x 2(hi,lo) uint4 -> no spill at cap 128.
// ---------------------------------------------------------------------------
template <int NS>
__device__ __forceinline__ void mfma_layer(
    const u32* __restrict__ whi, const u32* __restrict__ wlo,
    const float* __restrict__ bias,
    u32* __restrict__ sAct, int wave, int lane) {
    const int r = lane & 15, g = lane >> 4;
    f32x4 acc[2][4];
#pragma unroll
    for (int a = 0; a < 2; ++a)
#pragma unroll
        for (int b = 0; b < 4; ++b) acc[a][b] = f32x4{0.0f, 0.0f, 0.0f, 0.0f};

#pragma unroll 2
    for (int s = 0; s < NS; ++s) {
        half8 ah[2], al[2];
#pragma unroll
        for (int tt = 0; tt < 2; ++tt) {
            int idx = (((wave * 2 + tt) * NS + s) * 64 + lane) * 4;
            ah[tt] = __builtin_bit_cast(half8, *(const uint4*)(whi + idx));
            al[tt] = __builtin_bit_cast(half8, *(const uint4*)(wlo + idx));
        }
#pragma unroll
        for (int p = 0; p < 4; ++p) {
            int rr = p * 16 + r;
            int u = (s * 4 + g) ^ (rr & 31);
            half8 bh = __builtin_bit_cast(half8, *(const uint4*)(sAct + rr * 128 + u * 4));
#pragma unroll
            for (int tt = 0; tt < 2; ++tt) {
                acc[tt][p] = __builtin_amdgcn_mfma_f32_16x16x32_f16(al[tt], bh, acc[tt][p], 0, 0, 0);
                acc[tt][p] = __builtin_amdgcn_mfma_f32_16x16x32_f16(ah[tt], bh, acc[tt][p], 0, 0, 0);
            }
        }
    }
    __syncthreads();   // all reads of sAct done before overwrite

    // epilogue: bias + relu + f16 RNE + LDS write
    // D mapping: col px = 16p + (lane&15), row j' = 16T + 4g + e
#pragma unroll
    for (int tt = 0; tt < 2; ++tt) {
        int T = wave * 2 + tt;
        int jb = T * 16 + g * 4;
        float bv0 = bias[jb + 0], bv1 = bias[jb + 1];
        float bv2 = bias[jb + 2], bv3 = bias[jb + 3];
#pragma unroll
        for (int p = 0; p < 4; ++p) {
            float v0 = fmaxf(acc[tt][p][0] + bv0, 0.0f);
            float v1 = fmaxf(acc[tt][p][1] + bv1, 0.0f);
            float v2 = fmaxf(acc[tt][p][2] + bv2, 0.0f);
            float v3 = fmaxf(acc[tt][p][3] + bv3, 0.0f);
            int rr = p * 16 + r;
            int u = (2 * T + (g >> 1)) ^ (rr & 31);
            int a = rr * 128 + u * 4 + (g & 1) * 2;
            sAct[a]     = pk(h16(v0), h16(v1));
            sAct[a + 1] = pk(h16(v2), h16(v3));
        }
    }
    __syncthreads();
}

// ---------------------------------------------------------------------------
// Fused LIIF kernel: feature build -> 4 MFMA layers -> small final layer.
// 512 thr / 8 waves; launch_bounds(512,4): cap 128 regs, demand ~100 -> no spill.
// [r6 PMC: (256,4) spilled 1.25 GB; r7: (256,3) still spilled ~360 MB]
// ---------------------------------------------------------------------------
extern "C" __global__ void __launch_bounds__(NTHR, 4)
liif_mfma(const float* __restrict__ x, const float* __restrict__ coord,
          const float* __restrict__ cell, const float* __restrict__ lr,
          const float* __restrict__ b0, const float* __restrict__ b1,
          const float* __restrict__ b2, const float* __restrict__ b3,
          const float* __restrict__ W4, const float* __restrict__ b4,
          const u32* __restrict__ ws, float* __restrict__ out) {
    __shared__ u32 sAct[PPB * 128];   // 32 KB
    const int tid = threadIdx.x;
    const int wave = tid >> 6, lane = tid & 63;

    // ---------------- stage 1: 71-dim feature -> LDS f16 --------------------
    // 8 threads per pixel; each loads 8 channels = one 16B unit.
    {
        const int px = tid >> 3, sub = tid & 7;
        const int gg = blockIdx.x * PPB + px;
        const int b = gg / (HQ * WQ);
        const float gy = coord[(size_t)gg * 2 + 0];
        const float gx = coord[(size_t)gg * 2 + 1];
        bool vmain = true;
        const int ixn = nearest_idx(gx, vmain);
        const int iyn = nearest_idx(gy, vmain);

        const float* xb = x + (((size_t)b * NC) * HFD + iyn) * HFD + ixn;
        u32 hbuf[4];
#pragma unroll
        for (int e = 0; e < 4; ++e) {
            int c = sub * 8 + e * 2;
            float v0 = vmain ? xb[(size_t)c * (HFD * HFD)] : 0.0f;
            float v1 = vmain ? xb[(size_t)(c + 1) * (HFD * HFD)] : 0.0f;
            hbuf[e] = pk(h16(v0), h16(v1));
        }
        {
            int u = sub ^ (px & 31);
            *(uint4*)(sAct + px * 128 + u * 4) = make_uint4(hbuf[0], hbuf[1], hbuf[2], hbuf[3]);
        }
        if (sub == 0) {
            // extras: j = 64..71 -> logical unit 8
            float qyc = vmain ? ((2.0f * (float)iyn + 1.0f) / 48.0f - 1.0f) : 0.0f;
            float qxc = vmain ? ((2.0f * (float)ixn + 1.0f) / 48.0f - 1.0f) : 0.0f;
            float f64v = (gy - qyc) * 48.0f;
            float f65v = (gx - qxc) * 48.0f;
            float f66v = cell[b * 2 + 0] * 48.0f;
            float f67v = cell[b * 2 + 1] * 48.0f;

            // rgb_std over 4 diagonally shifted nearest LR samples (ddof=1)
            const float c148 = (float)(1.0 / 48.0);
            const float LO = (float)(-1.0 + 1e-6);
            const float HI = (float)(1.0 - 1e-6);
            float v[4][3];
#pragma unroll
            for (int a = 0; a < 2; ++a) {
                const float vx = (a == 0) ? -c148 : c148;
#pragma unroll
                for (int qq = 0; qq < 2; ++qq) {
                    const float vy = (qq == 0) ? -c148 : c148;
                    float cy = (gy + vx) + 1e-6f;
                    cy = fminf(fmaxf(cy, LO), HI);
                    float cx = (gx + vy) + 1e-6f;
                    cx = fminf(fmaxf(cx, LO), HI);
                    bool vv = true;
                    int jx = nearest_idx(cx, vv);
                    int jy = nearest_idx(cy, vv);
                    int si = a * 2 + qq;
#pragma unroll
                    for (int ch = 0; ch < 3; ++ch)
                        v[si][ch] = vv ? lr[(((size_t)b * 3 + ch) * HFD + jy) * HFD + jx] : 0.0f;
                }
            }
            float sd[3];
#pragma unroll
            for (int ch = 0; ch < 3; ++ch) {
                float mean = (((v[0][ch] + v[1][ch]) + v[2][ch]) + v[3][ch]) / 4.0f;
                float d0 = v[0][ch] - mean, d1 = v[1][ch] - mean;
                float d2 = v[2][ch] - mean, d3 = v[3][ch] - mean;
                float var = (((d0 * d0 + d1 * d1) + d2 * d2) + d3 * d3) / 3.0f;
                sd[ch] = sqrtf(var);
            }
            int u = 8 ^ (px & 31);
            *(uint4*)(sAct + px * 128 + u * 4) =
                make_uint4(pk(h16(f64v), h16(f65v)), pk(h16(f66v), h16(f67v)),
                           pk(h16(sd[0]), h16(sd[1])), pk(h16(sd[2]), 0));
        } else if (sub <= 3) {
            // zero-pad logical units 9..11 (k = 72..95)
            int u = (8 + sub) ^ (px & 31);
            *(uint4*)(sAct + px * 128 + u * 4) = make_uint4(0, 0, 0, 0);
        }
    }
    __syncthreads();

    // ---------------- 4 hidden layers on the matrix pipe --------------------
    mfma_layer<3>(ws + O0H, ws + O0L, b0, sAct, wave, lane);
    mfma_layer<8>(ws + O1H, ws + O1L, b1, sAct, wave, lane);
    mfma_layer<8>(ws + O2H, ws + O2L, b2, sAct, wave, lane);
    mfma_layer<8>(ws + O3H, ws + O3L, b3, sAct, wave, lane);

    // ---------------- final 256 -> 3 (VALU, tiny) ---------------------------
    if (tid < PPB * 3) {
        int px = tid / 3, o = tid - px * 3;
        float acc = 0.0f;
        for (int u = 0; u < 32; ++u) {
            int up = u ^ (px & 31);
            const u32* ph = sAct + px * 128 + up * 4;
#pragma unroll
            for (int uu = 0; uu < 4; ++uu) {
                u32 hv = ph[uu];
                int j = u * 8 + uu * 2;
                acc = __builtin_fmaf(f16lo(hv), W4[j * 3 + o], acc);
                acc = __builtin_fmaf(f16hi(hv), W4[(j + 1) * 3 + o], acc);
            }
        }
        acc += b4[o];
        int gg = blockIdx.x * PPB + px;
        int b = gg / (HQ * WQ);
        int rem = gg - b * (HQ * WQ);
        out[((size_t)(b * 3 + o)) * (HQ * WQ) + rem] = acc;
    }
}

extern "C" void kernel_launch(void* const* d_in, const int* in_sizes, int n_in,
                              void* d_out, int out_size, void* d_ws, size_t ws_size,
                              hipStream_t stream) {
    const float* x     = (const float*)d_in[0];
    const float* coord = (const float*)d_in[1];
    const float* cell  = (const float*)d_in[2];
    const float* lr    = (const float*)d_in[3];
    const float* W0    = (const float*)d_in[4];
    const float* b0    = (const float*)d_in[5];
    const float* W1    = (const float*)d_in[6];
    const float* b1    = (const float*)d_in[7];
    const float* W2    = (const float*)d_in[8];
    const float* b2    = (const float*)d_in[9];
    const float* W3    = (const float*)d_in[10];
    const float* b3    = (const float*)d_in[11];
    const float* W4    = (const float*)d_in[12];
    const float* b4    = (const float*)d_in[13];
    u32* ws = (u32*)d_ws;

    pack_w<<<dim3(432), dim3(256), 0, stream>>>(W0, W1, W2, W3, ws);
    liif_mfma<<<dim3(NPIX / PPB), dim3(NTHR), 0, stream>>>(
        x, coord, cell, lr, b0, b1, b2, b3, W4, b4, ws, (float*)d_out);
}